// Round 15
// baseline (551.115 us; speedup 1.0000x reference)
//
#include <hip/hip_runtime.h>
#include <hip/hip_bf16.h>
#include <stdint.h>

// ---------------------------------------------------------------------------
// Types
// ---------------------------------------------------------------------------
typedef __bf16 bf16x8 __attribute__((ext_vector_type(8)));
typedef float  f32x4  __attribute__((ext_vector_type(4)));

typedef __attribute__((address_space(1))) void gvoid;
typedef __attribute__((address_space(3))) void lvoid;

__device__ __forceinline__ void async16(void* lds, const void* g) {
    __builtin_amdgcn_global_load_lds((gvoid*)g, (lvoid*)lds, 16, 0, 0);
}

__device__ __forceinline__ float fexp2(float x) {
    return __builtin_amdgcn_exp2f(x);  // v_exp_f32
}

// ---------------------------------------------------------------------------
// Prep: X f32->bf16 (blocks >= 12288) + all weight transposes (blocks < 12288)
// ---------------------------------------------------------------------------
__global__ void prep_all(const float* __restrict__ X, __hip_bfloat16* __restrict__ Xb,
                         const float* __restrict__ wq, const float* __restrict__ wk,
                         const float* __restrict__ wv, const float* __restrict__ wo,
                         const float* __restrict__ w1, const float* __restrict__ w2,
                         __hip_bfloat16* __restrict__ Wcat,
                         __hip_bfloat16* __restrict__ Wot,
                         __hip_bfloat16* __restrict__ W1t,
                         __hip_bfloat16* __restrict__ W2t) {
    const int tix = blockIdx.x;
    if (tix >= 12288) {  // ---- cvt X ----
        const int bi = tix - 12288;
        const int tid = threadIdx.y * 32 + threadIdx.x;
        const long i = ((long)bi * 256 + tid) * 4;
        float4 v = *(const float4*)(X + i);
        __hip_bfloat162* d = (__hip_bfloat162*)(Xb + i);
        d[0] = __float22bfloat162_rn(make_float2(v.x, v.y));
        d[1] = __float22bfloat162_rn(make_float2(v.z, v.w));
        return;
    }
    // ---- weight transpose f32 [R][C] -> bf16 [C][R] ----
    __shared__ float t[32][33];
    const float* in;
    __hip_bfloat16* out;
    int R, C, cx, cy;
    if (tix < 4096) {
        int wid = tix >> 10, tile = tix & 1023;
        const float* srcs[4] = {wq, wk, wv, wo};
        __hip_bfloat16* dsts[4] = {Wcat, Wcat + 1024 * 1024, Wcat + 2 * 1024 * 1024, Wot};
        in = srcs[wid]; out = dsts[wid];
        R = 1024; C = 1024; cx = tile & 31; cy = tile >> 5;
    } else if (tix < 8192) {
        int tile = tix - 4096;
        in = w1; out = W1t; R = 1024; C = 4096;
        cx = tile & 127; cy = tile >> 7;
    } else {
        int tile = tix - 8192;
        in = w2; out = W2t; R = 4096; C = 1024;
        cx = tile & 31; cy = tile >> 5;
    }
    const int c0 = cx * 32, r0 = cy * 32;
    const int tx = threadIdx.x, ty = threadIdx.y;
#pragma unroll
    for (int i = 0; i < 4; ++i) {
        int r = r0 + ty + i * 8;
        t[ty + i * 8][tx] = in[(long)r * C + c0 + tx];
    }
    __syncthreads();
#pragma unroll
    for (int i = 0; i < 4; ++i) {
        int c = c0 + ty + i * 8;
        out[(long)c * R + r0 + tx] = __float2bfloat16(t[tx][ty + i * 8]);
    }
}

// ---------------------------------------------------------------------------
// Fused attention, 2-pass, max-free softmax (exp2).
// Phase 2: P -> sP (bf16) only; attn f32 written back from sP via vectorized
// f32x4 nt stores (16 vmem ops/thread/iter instead of 64 scalars).
// Counted drain: 8 DMAs older than <=16 stores -> vmcnt(16) at iter end.
// ---------------------------------------------------------------------------
#define RBAR asm volatile("s_barrier" ::: "memory")

__global__ void __launch_bounds__(256, 2)
attn_fused(const __hip_bfloat16* __restrict__ QKb,
           const __hip_bfloat16* __restrict__ Vt,
           const int* __restrict__ mask,
           float* __restrict__ attn,
           __hip_bfloat16* __restrict__ Ctx) {
    __shared__ __align__(16) __hip_bfloat16 sK[128 * 64];      // 16 KB
    __shared__ __align__(16) __hip_bfloat16 sV[2][64 * 128];   // 2 x 16 KB
    __shared__ __align__(16) __hip_bfloat16 sP[128 * 64];      // 16 KB
    __shared__ float smadd[1024];

    const int tid = threadIdx.x, lane = tid & 63, wave = tid >> 6;
    const int r16 = lane & 15, kg = lane >> 4;
    const float SC2 = 0.125f * 1.44269504f;

    const int dd = blockIdx.x;
    const int wgt = (dd & 7) * 128 + (dd >> 3);
    const int xblk = wgt & 7, z = wgt >> 3;
    const int b = z >> 4, h = z & 15;
    const int row0 = xblk * 128;
    const int wrow = wave * 32;

    const __hip_bfloat16* Qz = QKb + ((long)b * 1024 + row0) * 2048 + h * 64;
    const __hip_bfloat16* Kz = QKb + (long)b * 1024 * 2048 + 1024 + h * 64;
    const __hip_bfloat16* Vz = Vt + (long)z * 64 * 1024;
    float* attnZ = attn + (long)z * 1024 * 1024 + (long)row0 * 1024;

    for (int i = tid; i < 1024; i += 256)
        smadd[i] = mask[b * 1024 + i] ? 0.f : -1.5e9f;

    bf16x8 qa[2][2];
#pragma unroll
    for (int m = 0; m < 2; ++m)
#pragma unroll
        for (int kf = 0; kf < 2; ++kf)
            qa[m][kf] = *(const bf16x8*)(Qz + (long)(wrow + m * 16 + r16) * 2048 + kf * 32 + kg * 8);

    float lrow[2][4];
#pragma unroll
    for (int m = 0; m < 2; ++m)
#pragma unroll
        for (int i = 0; i < 4; ++i) lrow[m][i] = 0.f;

    const int ssw = (r16 & 7) << 4;

    auto stageK = [&](char* dst, int ct) {
#pragma unroll
        for (int j = 0; j < 4; ++j) {
            int c = wave * 4 + j;
            int s = c * 8 + (lane >> 3);
            int cb = (lane & 7) * 16;
            async16(dst + c * 1024,
                    (const char*)(Kz + (long)(ct * 128 + s) * 2048) + (cb ^ ((s & 7) << 4)));
        }
    };
    auto stageV = [&](int ct, int buf) {
#pragma unroll
        for (int j = 0; j < 4; ++j) {
            int c = wave * 4 + j;
            int dv = c * 4 + (lane >> 4);
            int cb = (lane & 15) * 16;
            async16((char*)sV[buf] + c * 1024,
                    (const char*)(Vz + (long)dv * 1024 + ct * 128) + (cb ^ ((dv & 7) << 4)));
        }
    };

    // ---------------- phase 1: row sums (ping-pong K: sK / sV[0]) ----------------
    char* kbuf0 = (char*)sK;
    char* kbuf1 = (char*)sV[0];
    stageK(kbuf0, 0);

    for (int ct = 0; ct < 8; ++ct) {
        asm volatile("s_waitcnt vmcnt(0)" ::: "memory");
        __syncthreads();
        if (ct < 7) stageK((ct & 1) ? kbuf0 : kbuf1, ct + 1);
        const char* base = (ct & 1) ? kbuf1 : kbuf0;

        f32x4 sacc[2][8];
#pragma unroll
        for (int m = 0; m < 2; ++m)
#pragma unroll
            for (int nf = 0; nf < 8; ++nf) sacc[m][nf] = f32x4{0.f, 0.f, 0.f, 0.f};

        __builtin_amdgcn_s_setprio(1);
#pragma unroll
        for (int nf = 0; nf < 8; ++nf) {
            const char* kr = base + (nf * 16 + r16) * 128;
            bf16x8 bv0 = *(const bf16x8*)(kr + ((kg * 16) ^ ssw));
            bf16x8 bv1 = *(const bf16x8*)(kr + ((64 + kg * 16) ^ ssw));
#pragma unroll
            for (int m = 0; m < 2; ++m) {
                sacc[m][nf] = __builtin_amdgcn_mfma_f32_16x16x32_bf16(qa[m][0], bv0, sacc[m][nf], 0, 0, 0);
                sacc[m][nf] = __builtin_amdgcn_mfma_f32_16x16x32_bf16(qa[m][1], bv1, sacc[m][nf], 0, 0, 0);
            }
        }
        __builtin_amdgcn_s_setprio(0);

        float madd[8];
#pragma unroll
        for (int nf = 0; nf < 8; ++nf) madd[nf] = smadd[ct * 128 + nf * 16 + r16];

#pragma unroll
        for (int m = 0; m < 2; ++m)
#pragma unroll
            for (int i = 0; i < 4; ++i) {
                float ts = 0.f;
#pragma unroll
                for (int nf = 0; nf < 8; ++nf)
                    ts += fexp2(sacc[m][nf][i] * SC2 + madd[nf]);
#pragma unroll
                for (int o = 1; o < 16; o <<= 1) ts += __shfl_xor(ts, o);
                lrow[m][i] += ts;
            }
    }

    float rinv[2][4];
#pragma unroll
    for (int m = 0; m < 2; ++m)
#pragma unroll
        for (int i = 0; i < 4; ++i) rinv[m][i] = 1.0f / lrow[m][i];

    f32x4 oacc[2][4];
#pragma unroll
    for (int m = 0; m < 2; ++m)
#pragma unroll
        for (int nf = 0; nf < 4; ++nf) oacc[m][nf] = f32x4{0.f, 0.f, 0.f, 0.f};

    // ---------------- phase 2: P -> sP -> (PV, attn write-back) ----------------
    __syncthreads();
    stageK((char*)sK, 0);
    stageV(0, 0);
    asm volatile("s_waitcnt vmcnt(0)" ::: "memory");
    __syncthreads();

    for (int ct = 0; ct < 8; ++ct) {
        f32x4 sacc[2][8];
#pragma unroll
        for (int m = 0; m < 2; ++m)
#pragma unroll
            for (int nf = 0; nf < 8; ++nf) sacc[m][nf] = f32x4{0.f, 0.f, 0.f, 0.f};

        __builtin_amdgcn_s_setprio(1);
#pragma unroll
        for (int nf = 0; nf < 8; ++nf) {
            const char* kr = (const char*)sK + (nf * 16 + r16) * 128;
            bf16x8 bv0 = *(const bf16x8*)(kr + ((kg * 16) ^ ssw));
            bf16x8 bv1 = *(const bf16x8*)(kr + ((64 + kg * 16) ^ ssw));
#pragma unroll
            for (int m = 0; m < 2; ++m) {
                sacc[m][nf] = __builtin_amdgcn_mfma_f32_16x16x32_bf16(qa[m][0], bv0, sacc[m][nf], 0, 0, 0);
                sacc[m][nf] = __builtin_amdgcn_mfma_f32_16x16x32_bf16(qa[m][1], bv1, sacc[m][nf], 0, 0, 0);
            }
        }
        __builtin_amdgcn_s_setprio(0);

        RBAR;
        if (ct < 7) {
            stageK((char*)sK, ct + 1);
            stageV(ct + 1, (ct + 1) & 1);
        }
        asm volatile("" ::: "memory");  // pin: DMA issue BEFORE the stores below

        float madd[8];
#pragma unroll
        for (int nf = 0; nf < 8; ++nf) madd[nf] = smadd[ct * 128 + nf * 16 + r16];

        const char* sVb = (const char*)sV[ct & 1];

#pragma unroll
        for (int half = 0; half < 2; ++half) {
            // ---- P -> sP (bf16, swizzled) ----
#pragma unroll
            for (int m = 0; m < 2; ++m)
#pragma unroll
                for (int nf = 0; nf < 4; ++nf) {
                    const int nfg = half * 4 + nf;
                    const int scl = nf * 16 + r16;
#pragma unroll
                    for (int i = 0; i < 4; ++i) {
                        int q = wrow + m * 16 + kg * 4 + i;
                        float p = fexp2(sacc[m][nfg][i] * SC2 + madd[nfg]) * rinv[m][i];
                        *(__hip_bfloat16*)((char*)sP + q * 128 + ((scl * 2) ^ ((q & 7) << 4))) =
                            __float2bfloat16(p);
                    }
                }

            // ---- PV for this half (own-wave sP rows) ----
            __builtin_amdgcn_s_setprio(1);
#pragma unroll
            for (int ks = 0; ks < 2; ++ks) {
                const int ksg = half * 2 + ks;
                bf16x8 pa[2], vv[4];
#pragma unroll
                for (int m = 0; m < 2; ++m)
                    pa[m] = *(const bf16x8*)((const char*)sP + (wrow + m * 16 + r16) * 128 +
                                             ((ks * 64 + kg * 16) ^ ssw));
#pragma unroll
                for (int nf = 0; nf < 4; ++nf)
                    vv[nf] = *(const bf16x8*)(sVb + (nf * 16 + r16) * 256 +
                                              ((ksg * 64 + kg * 16) ^ ssw));
#pragma unroll
                for (int m = 0; m < 2; ++m)
#pragma unroll
                    for (int nf = 0; nf < 4; ++nf)
                        oacc[m][nf] = __builtin_amdgcn_mfma_f32_16x16x32_bf16(pa[m], vv[nf], oacc[m][nf], 0, 0, 0);
            }
            __builtin_amdgcn_s_setprio(0);

            // ---- write-back: sP (this wave's 32 rows x 64 cols) -> attn f32 ----
#pragma unroll
            for (int t = 0; t < 4; ++t) {
                const int q = wrow + t * 8 + (lane >> 3);
                const int cb = (lane & 7) * 16;  // byte offset of 8 bf16 in row
                bf16x8 v = *(const bf16x8*)((const char*)sP + q * 128 + (cb ^ ((q & 7) << 4)));
                f32x4 f0, f1;
#pragma unroll
                for (int e = 0; e < 4; ++e) {
                    f0[e] = __bfloat162float(((const __hip_bfloat16*)&v)[e]);
                    f1[e] = __bfloat162float(((const __hip_bfloat16*)&v)[e + 4]);
                }
                float* dst = attnZ + (long)q * 1024 + ct * 128 + half * 64 + (lane & 7) * 8;
                __builtin_nontemporal_store(f0, (f32x4*)dst);
                __builtin_nontemporal_store(f1, (f32x4*)(dst + 4));
            }
        }

        if (ct < 7) {
            // 8 K/V DMAs are OLDER than the <=16 stores above: waiting to <=16
            // outstanding retires the DMAs while stores keep draining.
            asm volatile("s_waitcnt vmcnt(16)" ::: "memory");
            RBAR;
        }
    }

#pragma unroll
    for (int m = 0; m < 2; ++m)
#pragma unroll
        for (int nf = 0; nf < 4; ++nf)
#pragma unroll
            for (int i = 0; i < 4; ++i) {
                int q = wrow + m * 16 + kg * 4 + i;
                Ctx[((long)b * 1024 + row0 + q) * 1024 + h * 64 + nf * 16 + r16] =
                    __float2bfloat16(oacc[m][nf][i]);
            }
}

// ---------------------------------------------------------------------------
// Shared GEMM macros
// ---------------------------------------------------------------------------
#define RDA(BUF, PM, ML, KS) \
    (*(const bf16x8*)(aRd + (BUF)*32768 + (PM)*16384 + (ML)*2048 + ((((KS)*64) + kg*16) ^ sw)))
#define RDB(BUF, PN, NL, KS) \
    (*(const bf16x8*)(bRd + (BUF)*32768 + (PN)*16384 + (NL)*2048 + ((((KS)*64) + kg*16) ^ sw)))
#define LOAD_A(BUF, PM)                          \
    _Pragma("unroll") for (int ml = 0; ml < 4; ++ml) \
    _Pragma("unroll") for (int ks = 0; ks < 2; ++ks) \
        a[ml][ks] = RDA(BUF, PM, ml, ks)
#define LOAD_B(DST, BUF, PN)                     \
    _Pragma("unroll") for (int nl = 0; nl < 2; ++nl) \
    _Pragma("unroll") for (int ks = 0; ks < 2; ++ks) \
        DST[nl][ks] = RDB(BUF, PN, nl, ks)
#define MFMA16(PM, PN, BB)                                                   \
    __builtin_amdgcn_s_setprio(1);                                           \
    _Pragma("unroll") for (int ks = 0; ks < 2; ++ks)                         \
    _Pragma("unroll") for (int ml = 0; ml < 4; ++ml)                         \
    _Pragma("unroll") for (int nl = 0; nl < 2; ++nl)                         \
        acc[(PM)*4 + ml][(PN)*2 + nl] = __builtin_amdgcn_mfma_f32_16x16x32_bf16( \
            a[ml][ks], BB[nl][ks], acc[(PM)*4 + ml][(PN)*2 + nl], 0, 0, 0);  \
    __builtin_amdgcn_s_setprio(0)
#define BAR asm volatile("s_barrier" ::: "memory")
#define RDB128(BUF, NL, KS) \
    (*(const bf16x8*)(bRd + (BUF)*16384 + (NL)*2048 + ((((KS)*64) + kg*16) ^ sw)))
#define LOAD_B128(DST, BUF)                      \
    _Pragma("unroll") for (int nl = 0; nl < 2; ++nl) \
    _Pragma("unroll") for (int ks = 0; ks < 2; ++ks) \
        DST[nl][ks] = RDB128(BUF, nl, ks)
#define MFMA16N(PM, BB)                                                      \
    __builtin_amdgcn_s_setprio(1);                                           \
    _Pragma("unroll") for (int ks = 0; ks < 2; ++ks)                         \
    _Pragma("unroll") for (int ml = 0; ml < 4; ++ml)                         \
    _Pragma("unroll") for (int nl = 0; nl < 2; ++nl)                         \
        acc[(PM)*4 + ml][nl] = __builtin_amdgcn_mfma_f32_16x16x32_bf16(      \
            a[ml][ks], BB[nl][ks], acc[(PM)*4 + ml][nl], 0, 0, 0);           \
    __builtin_amdgcn_s_setprio(0)

// ---------------------------------------------------------------------------
// 256x256 8-phase GEMM — FFN1 (N=4096).
// ---------------------------------------------------------------------------
__global__ void __launch_bounds__(512, 2)
gemm256(const __hip_bfloat16* __restrict__ A, int lda,
        const __hip_bfloat16* __restrict__ Bt, int ldb,
        int K, int Mtiles,
        const float* __restrict__ bias, int relu,
        __hip_bfloat16* __restrict__ C, int ldc) {
    __shared__ __align__(16) char lds[131072];
    const int NT = K >> 6;
    const int tid = threadIdx.x, lane = tid & 63, wave = tid >> 6;
    const int r16 = lane & 15, kg = lane >> 4;
    const int wr = wave >> 2, wc = wave & 3;
    const int sw = (r16 & 7) << 4;

    const int nwg = gridDim.x;
    const int q8 = nwg >> 3, r8 = nwg & 7;
    const int xcd = blockIdx.x & 7, rest = blockIdx.x >> 3;
    const int wg = (xcd < r8 ? xcd * (q8 + 1) : r8 * (q8 + 1) + (xcd - r8) * q8) + rest;
    const int tm = wg % Mtiles, tn = wg / Mtiles;
    const long row0 = (long)tm * 256, col0 = (long)tn * 256;

    const int idx = tid >> 3;
    const int slotp = ((tid & 7) ^ (idx & 7)) * 8;
    const __hip_bfloat16* aSrc[4];
    const __hip_bfloat16* bSrc[4];
#pragma unroll
    for (int j = 0; j < 4; ++j) {
        long ar = row0 + (j & 1) * 128 + (j >> 1) * 64 + idx;
        aSrc[j] = A + ar * lda + slotp;
        long br = col0 + ((j & 1) * 2 + (tid >> 8)) * 64 + (j >> 1) * 32 + (idx & 31);
        bSrc[j] = Bt + br * ldb + slotp;
    }

    char* ldsA = lds;
    char* ldsB = lds + 65536;
    const int stDst = wave * 1024;
    auto stA = [&](int v, int j) {
        async16(ldsA + ((v & 1) << 15) + (j << 13) + stDst, aSrc[j] + (v << 6));
    };
    auto stB = [&](int v, int j) {
        async16(ldsB + ((v & 1) << 15) + (j << 13) + stDst, bSrc[j] + (v << 6));
    };

    stA(0, 0); stA(0, 1); stB(0, 0); stB(0, 1);
    stA(0, 2); stA(0, 3); stB(0, 2); stB(0, 3);
    stA(1, 0); stA(1, 1); stB(1, 0); stB(1, 1);
    asm volatile("s_waitcnt vmcnt(4)" ::: "memory");
    BAR;

    f32x4 acc[8][4] = {};
    const char* aRd = ldsA + wr * 8192 + r16 * 128;
    const char* bRd = ldsB + wc * 4096 + r16 * 128;

    for (int u = 0; u < NT; u += 2) {
        const bool more = (u + 2) < NT;
        bf16x8 a[4][2], b0[2][2], b1[2][2];

        LOAD_A(0, 0);
        LOAD_B(b0, 0, 0);
        stA(u + 1, 2); stA(u + 1, 3);
        MFMA16(0, 0, b0);
        BAR;

        LOAD_B(b1, 0, 1);
        stB(u + 1, 2); stB(u + 1, 3);
        MFMA16(0, 1, b1);
        BAR;

        LOAD_A(0, 1);
        if (more) { stA(u + 2, 0); stA(u + 2, 1); }
        MFMA16(1, 0, b0);
        BAR;

        if (more) {
            stB(u + 2, 0); stB(u + 2, 1);
            asm volatile("s_waitcnt vmcnt(4)" ::: "memory");
        } else {
            asm volatile("s_waitcnt vmcnt(0)" ::: "memory");
        }
        MFMA16(1, 1, b1);
        BAR;

        LOAD_A(1, 0);
        LOAD_B(b0, 1, 0);
        if (more) { stA(u + 2, 2); stA(u + 2, 3); }
        MFMA16(0, 0, b0);
        BAR;

        LOAD_B(b1, 1, 1);
        if (more) { stB(u + 2, 2); stB(u + 2, 3); }
        MFMA16(0, 1, b1);
        BAR;

        LOAD_A(1, 1);
        if (more) { stA(u + 3, 0); stA(u + 3, 1); }
        MFMA16(1, 0, b0);
        BAR;

        if (more) {
            stB(u + 3, 0); stB(u + 3, 1);
            asm volatile("s_waitcnt vmcnt(4)" ::: "memory");
        }
        MFMA16(1, 1, b1);
        BAR;
    }

    const long crow = row0 + wr * 128, ccol = col0 + wc * 64;
#pragma unroll
    for (int mf = 0; mf < 8; ++mf)
#pragma unroll
        for (int nf = 0; nf < 4; ++nf) {
            const long col = ccol + nf * 16 + r16;
            const float bs = bias ? bias[col] : 0.f;
#pragma unroll
            for (int i = 0; i < 4; ++i) {
                const long row = crow + mf * 16 + kg * 4 + i;
                float v = acc[mf][nf][i] + bs;
                if (relu) v = fmaxf(v, 0.f);
                C[row * (long)ldc + col] = __float2bfloat16(v);
            }
        }
}

// ---------------------------------------------------------------------------
// Merged QK + V dispatcher (R13-proven).
// ---------------------------------------------------------------------------
__global__ void __launch_bounds__(512, 2)
gemm_qkv(const __hip_bfloat16* __restrict__ A,
         const __hip_bfloat16* __restrict__ Wcat,
         __hip_bfloat16* __restrict__ QKb,
         __hip_bfloat16* __restrict__ Vt) {
    __shared__ __align__(16) char lds[131072];
    const int tid = threadIdx.x, lane = tid & 63, wave = tid >> 6;
    const int r16 = lane & 15, kg = lane >> 4;
    const int wr = wave >> 2, wc = wave & 3;
    const int sw = (r16 & 7) << 4;
    const int idx = tid >> 3;
    const int slotp = ((tid & 7) ^ (idx & 7)) * 8;
    const int stDst = wave * 1024;
    constexpr int NT = 16;  // K=1024

    if (blockIdx.x < 256) {
        const int id = blockIdx.x;
        const int xcd = id & 7, rest = id >> 3;
        const int wg = xcd * 32 + rest;
        const int tm = wg & 31, tn = wg >> 5;
        const long row0 = (long)tm * 256, col0 = (long)tn * 256;

        const __hip_bfloat16* aSrc[4];
        const __hip_bfloat16* bSrc[4];
#pragma unroll
        for (int j = 0; j < 4; ++j) {
            long ar = row0 + (j & 1) * 128 + (j >> 1) * 64 + idx;
            aSrc[j] = A + ar * 1024 + slotp;
            long br = col0 + ((j & 1) * 2 + (tid >> 8)) * 64 + (j >> 1) * 32 + (idx & 31);
            bSrc[j] = Wcat + br * 1024 + slotp;
        }

        char* ldsA = lds;
        char* ldsB = lds + 65536;
        auto stA = [&](int v, int j) {
            async16(ldsA + ((v & 1) << 15) + (j << 13) + stDst, aSrc[j] + (v << 6));
        };
        auto stB = [&](int v, int j) {
            async16(ldsB + ((v & 1) << 15) + (j << 13) + stDst, bSrc[j] + (v << 6));
        };

        stA(0, 0); stA(0, 1); stB(0, 0); stB(0, 1);
        stA(0, 2); stA(0, 3); stB(0, 2); stB(0, 3);
        stA(1, 0); stA(1, 1); stB(1, 0); stB(1, 1);
        asm volatile("s_waitcnt vmcnt(4)" ::: "memory");
        BAR;

        f32x4 acc[8][4] = {};
        const char* aRd = ldsA + wr * 8192 + r16 * 128;
        const char* bRd = ldsB + wc * 4096 + r16 * 128;

        for (int u = 0; u < NT; u += 2) {
            const bool more = (u + 2) < NT;
            bf16x8 a[4][2], b0[2][2], b1[2][2];

            LOAD_A(0, 0);
            LOAD_B(b0, 0, 0);
            stA(u + 1, 2); stA(u + 1, 3);
            MFMA16(0, 0, b0);
            BAR;

            LOAD_B(b1, 0, 1);
            stB(u + 1, 2); stB(u + 1, 3);
            MFMA16(0, 1, b1);
            BAR;

            LOAD_A(0, 1);
            if (more) { stA(u + 2, 0); stA(u + 2, 1); }
            MFMA16(1, 0, b0);
            BAR;

            if (more) {
                stB(u + 2, 0); stB(u + 2, 1);
                asm volatile("s_waitcnt vmcnt(4)" ::: "memory");
            } else {
                asm volatile("s_waitcnt vmcnt(0)" ::: "memory");
            }
            MFMA16(1, 1, b1);
            BAR;

            LOAD_A(1, 0);
            LOAD_B(b0, 1, 0);
            if (more) { stA(u + 2, 2); stA(u + 2, 3); }
            MFMA16(0, 0, b0);
            BAR;

            LOAD_B(b1, 1, 1);
            if (more) { stB(u + 2, 2); stB(u + 2, 3); }
            MFMA16(0, 1, b1);
            BAR;

            LOAD_A(1, 1);
            if (more) { stA(u + 3, 0); stA(u + 3, 1); }
            MFMA16(1, 0, b0);
            BAR;

            if (more) {
                stB(u + 3, 0); stB(u + 3, 1);
                asm volatile("s_waitcnt vmcnt(4)" ::: "memory");
            }
            MFMA16(1, 1, b1);
            BAR;
        }

        const long crow = row0 + wr * 128, ccol = col0 + wc * 64;
#pragma unroll
        for (int mf = 0; mf < 8; ++mf)
#pragma unroll
            for (int nf = 0; nf < 4; ++nf) {
                const long col = ccol + nf * 16 + r16;
#pragma unroll
                for (int i = 0; i < 4; ++i) {
                    const long row = crow + mf * 16 + kg * 4 + i;
                    QKb[row * 2048 + col] = __float2bfloat16(acc[mf][nf][i]);
                }
            }
    } else {
        const int id = blockIdx.x - 256;
        const int xcd = id & 7, rest = id >> 3;
        const int wg = xcd * 32 + rest;
        const int tm = wg & 31, tn = wg >> 5;
        const long row0 = (long)tm * 256, col0 = (long)tn * 128;
        const __hip_bfloat16* Bt = Wcat + (long)2048 * 1024;

        const __hip_bfloat16* aSrc[4];
        const __hip_bfloat16* bSrc[2];
#pragma unroll
        for (int j = 0; j < 4; ++j) {
            long ar = row0 + (j & 1) * 128 + (j >> 1) * 64 + idx;
            aSrc[j] = A + ar * 1024 + slotp;
        }
#pragma unroll
        for (int j = 0; j < 2; ++j) {
            long br = col0 + j * 64 + idx;
            bSrc[j] = Bt + br * 1024 + slotp;
        }

        char* ldsA = lds;
        char* ldsB = lds + 65536;
        auto stA = [&](int v, int j) {
            async16(ldsA + ((v & 1) << 15) + (j << 13) + stDst, aSrc[j] + (v << 6));
        };
        auto stB = [&](int v, int j) {
            async16(ldsB + ((v & 1) << 14) + (j << 13) + stDst, bSrc[j] + (v << 6));
        };

        stA(0, 0); stA(0, 1); stA(0, 2); stA(0, 3);
        stB(0, 0); stB(0, 1);
        stA(1, 0); stA(1, 1);
        stB(1, 0); stB(1, 1);
        asm volatile("s_waitcnt vmcnt(4)" ::: "memory");
        BAR;

        f32x4 acc[8][2] = {};
        const char* aRd = ldsA + wr * 8192 + r16 * 128;
        const char* bRd = ldsB + wc * 4096 + r16 * 128;

        for (int u = 0; u < NT; u += 2) {
            const bool more = (u + 2) < NT;
            bf16x8 a[4][2], b0[2][2], b1[2][2];

            LOAD_A(0, 0);
            LOAD_B128(b0, 0);
            stA(u + 1, 2); stA(u + 1, 3);
            MFMA16N(0, b0);
            BAR;

            LOAD_A(0, 1);
            if (more) {
                stA(u + 2, 0); stA(u + 2, 1);
                stB(u + 2, 0); stB(u + 2, 1);
                asm volatile("s_waitcnt vmcnt(4)" ::: "memory");
            } else {
                asm volatile("s_waitcnt vmcnt(0)" ::: "memory");
            }
            MFMA16N(1, b0);
            BAR;

            LOAD_A(1, 0);
            LOAD_B128(b1, 1);
            if (more) { stA(u + 2, 2); stA(u + 2, 3); }
            MFMA16N(0, b1);
            BAR;

            LOAD_A(1, 1);
            if (more) {
                stA(u + 3, 0); stA(u + 3, 1);
                stB(u + 3, 0); stB(u + 3, 1);
                asm volatile("s_waitcnt vmcnt(4)" ::: "memory");
            }
            MFMA16N(1, b1);
            BAR;
        }

        __hip_bfloat16* sT = (__hip_bfloat16*)lds;
        {
            const int cls = wc * 32;
            const int rls = wr * 128 + kg * 4;
#pragma unroll
            for (int mf = 0; mf < 8; ++mf)
#pragma unroll
                for (int nf = 0; nf < 2; ++nf) {
                    int cl = cls + nf * 16 + r16;
                    int rl = rls + mf * 16;
                    __hip_bfloat162 lo = __float22bfloat162_rn(make_float2(acc[mf][nf][0], acc[mf][nf][1]));
                    __hip_bfloat162 hi = __float22bfloat162_rn(make_float2(acc[mf][nf][2], acc[mf][nf][3]));
                    *(__hip_bfloat162*)(&sT[cl * 264 + rl]) = lo;
                    *(__hip_bfloat162*)(&sT[cl * 264 + rl + 2]) = hi;
                }
        }
        __syncthreads();
        {
            const int b = (int)(row0 >> 10);
            const int s_base = (int)(row0 & 1023);
#pragma unroll
            for (int j = 0; j < 8; ++j) {
                int dl = wave * 16 + j * 2 + (lane >> 5);
                int sc = (lane & 31) * 8;
                bf16x8 v = *(const bf16x8*)(&sT[dl * 264 + sc]);
                int dg = (int)col0 + dl;
                int z = b * 16 + (dg >> 6);
                int d = dg & 63;
                *(bf16x8*)(Vt + ((long)z * 64 + d) * 1024 + s_base + sc) = v;
            }
        }
    }
}

// ---------------------------------------------------------------------------
// 256x128-tile 4-phase GEMM — N=1024 shapes (Wo, FFN2): 256 blocks.
// ---------------------------------------------------------------------------
__global__ void __launch_bounds__(512, 2)
gemm256n128(const __hip_bfloat16* __restrict__ A, int lda,
            const __hip_bfloat16* __restrict__ Bt, int ldb,
            int K, int Mtiles,
            const float* __restrict__ bias, int relu,
            const float* __restrict__ resf,
            const __hip_bfloat16* __restrict__ resb, int ldres,
            float* __restrict__ Cf, __hip_bfloat16* __restrict__ Cb, int ldc) {
    __shared__ __align__(16) char lds[98304];  // A 2x32KB + B 2x16KB
    const int NT = K >> 6;
    const int tid = threadIdx.x, lane = tid & 63, wave = tid >> 6;
    const int r16 = lane & 15, kg = lane >> 4;
    const int wr = wave >> 2, wc = wave & 3;
    const int sw = (r16 & 7) << 4;

    const int nwg = gridDim.x;
    const int q8 = nwg >> 3, r8 = nwg & 7;
    const int xcd = blockIdx.x & 7, rest = blockIdx.x >> 3;
    const int wg = (xcd < r8 ? xcd * (q8 + 1) : r8 * (q8 + 1) + (xcd - r8) * q8) + rest;
    const int tm = wg % Mtiles, tn = wg / Mtiles;
    const long row0 = (long)tm * 256, col0 = (long)tn * 128;

    const int idx = tid >> 3;
    const int slotp = ((tid & 7) ^ (idx & 7)) * 8;
    const __hip_bfloat16* aSrc[4];
    const __hip_bfloat16* bSrc[2];
#pragma unroll
    for (int j = 0; j < 4; ++j) {
        long ar = row0 + (j & 1) * 128 + (j >> 1) * 64 + idx;
        aSrc[j] = A + ar * lda + slotp;
    }
#pragma unroll
    for (int j = 0; j < 2; ++j) {
        long br = col0 + j * 64 + idx;
        bSrc[j] = Bt + br * ldb + slotp;
    }

    char* ldsA = lds;
    char* ldsB = lds + 65536;
    const int stDst = wave * 1024;
    auto stA = [&](int v, int j) {
        async16(ldsA + ((v & 1) << 15) + (j << 13) + stDst, aSrc[j] + (v << 6));
    };
    auto stB = [&](int v, int j) {
        async16(ldsB + ((v & 1) << 14) + (j << 13) + stDst, bSrc[j] + (v << 6));
    };

    stA(0, 0); stA(0, 1); stA(0, 2); stA(0, 3);
    stB(0, 0); stB(0, 1);
    stA(1, 0); stA(1, 1);
    stB(1, 0); stB(1, 1);
    asm volatile("s_waitcnt vmcnt(4)" ::: "memory");
    BAR;

    f32x4 acc[8][2] = {};
    const char* aRd = ldsA + wr * 8192 + r16 * 128;
    const char* bRd = ldsB + wc * 4096 + r16 * 128;

    for (int u = 0; u < NT; u += 2) {
        const bool more = (u + 2) < NT;
        bf16x8 a[4][2], b0[2][2], b1[2][2];

        LOAD_A(0, 0);
        LOAD_B128(b0, 0);
        stA(u + 1, 2); stA(u + 1, 3);
        MFMA16N(0, b0);
        BAR;

        LOAD_A(0, 1);
        if (more) {
            stA(u + 2, 0); stA(u + 2, 1);
            stB(u + 2, 0); stB(u + 2, 1);
            asm volatile("s_waitcnt vmcnt(4)" ::: "memory");
        } else {
            asm volatile("s_waitcnt vmcnt(0)" ::: "memory");
        }
        MFMA16N(1, b0);
        BAR;

        LOAD_A(1, 0);
        LOAD_B128(b1, 1);
        if (more) { stA(u + 2, 2); stA(u + 2, 3); }
        MFMA16N(0, b1);
        BAR;

        LOAD_A(1, 1);
        if (more) {
            stA(u + 3, 0); stA(u + 3, 1);
            stB(u + 3, 0); stB(u + 3, 1);
            asm volatile("s_waitcnt vmcnt(4)" ::: "memory");
        }
        MFMA16N(1, b1);
        BAR;
    }

    const long crow = row0 + wr * 128, ccol = col0 + wc * 32;
#pragma unroll
    for (int mf = 0; mf < 8; ++mf)
#pragma unroll
        for (int nf = 0; nf < 2; ++nf) {
            const long col = ccol + nf * 16 + r16;
            const float bs = bias ? bias[col] : 0.f;
#pragma unroll
            for (int i = 0; i < 4; ++i) {
                const long row = crow + mf * 16 + kg * 4 + i;
                float v = acc[mf][nf][i] + bs;
                if (relu) v = fmaxf(v, 0.f);
                if (resf) v += resf[row * (long)ldres + col];
                if (resb) v += __bfloat162float(resb[row * (long)ldres + col]);
                const long off = row * (long)ldc + col;
                if (Cf) __builtin_nontemporal_store(v, Cf + off);
                if (Cb) Cb[off] = __float2bfloat16(v);
            }
        }
}

// ---------------------------------------------------------------------------
// Launch
// ---------------------------------------------------------------------------
extern "C" void kernel_launch(void* const* d_in, const int* in_sizes, int n_in,
                              void* d_out, int out_size, void* d_ws, size_t ws_size,
                              hipStream_t stream) {
    const int B = 8, S = 1024, D = 1024, DFF = 4096;
    const long SD = (long)B * S * D;  // 8M

    const float* X  = (const float*)d_in[0];
    const int*  msk = (const int*)d_in[1];
    const float* wq = (const float*)d_in[3];
    const float* wk = (const float*)d_in[4];
    const float* wv = (const float*)d_in[5];
    const float* wo = (const float*)d_in[6];
    const float* w1 = (const float*)d_in[7];
    const float* b1 = (const float*)d_in[8];
    const float* w2 = (const float*)d_in[9];
    const float* b2 = (const float*)d_in[10];

    float* out  = (float*)d_out;
    float* attn = out + SD;

    char* ws = (char*)d_ws;
    auto alloc = [&](size_t bytes) {
        char* p = ws;
        ws += (bytes + 255) & ~(size_t)255;
        return p;
    };
    __hip_bfloat16* Xb   = (__hip_bfloat16*)alloc(SD * 2);
    __hip_bfloat16* QKb  = (__hip_bfloat16*)alloc(SD * 4);   // [8192][2048]
    __hip_bfloat16* Vt   = (__hip_bfloat16*)alloc(SD * 2);   // [128][64][1024]
    __hip_bfloat16* Ctx  = (__hip_bfloat16*)alloc(SD * 2);
    __hip_bfloat16* EncB = (__hip_bfloat16*)alloc(SD * 2);
    __hip_bfloat16* Hb   = (__hip_bfloat16*)alloc((long)B * S * DFF * 2);
    __hip_bfloat16* Wcat = (__hip_bfloat16*)alloc((long)3 * D * D * 2);  // [3072][1024]
    __hip_bfloat16* Wot  = (__hip_bfloat16*)alloc((long)D * D * 2);
    __hip_bfloat16* W1t  = (__hip_bfloat16*)alloc((long)D * DFF * 2);
    __hip_bfloat16* W2t  = (__hip_bfloat16*)alloc((long)D * DFF * 2);
    (void)ws_size; (void)in_sizes; (void)n_in; (void)out_size;

    dim3 tb(32, 8);
    prep_all<<<dim3(12288 + 8192), tb, 0, stream>>>(X, Xb, wq, wk, wv, wo, w1, w2,
                                                    Wcat, Wot, W1t, W2t);

    // QK [8192][2048] + V->Vt in ONE dispatch (512 blocks)
    gemm_qkv<<<dim3(512), 512, 0, stream>>>(Xb, Wcat, QKb, Vt);

    // fused attention: attn f32 + ctx bf16
    attn_fused<<<dim3(1024), 256, 0, stream>>>(QKb, Vt, msk, attn, Ctx);

    // enc = ctx @ Wo + X  -> bf16   (256x128, 256 blocks)
    gemm256n128<<<dim3(32 * 8), 512, 0, stream>>>(
        Ctx, D, Wot, D, D, 32,
        nullptr, 0, X, nullptr, D,
        nullptr, EncB, D);

    // h = relu(enc @ W1 + b1)   (256^2, 512 blocks)
    gemm256<<<dim3(32 * 16), 512, 0, stream>>>(
        EncB, D, W1t, D, D, 32, b1, 1, Hb, DFF);

    // out = h @ W2 + b2 + enc (bf16 residual)   (256x128, 256 blocks)
    gemm256n128<<<dim3(32 * 8), 512, 0, stream>>>(
        Hb, DFF, W2t, DFF, DFF, 32,
        b2, 0, nullptr, EncB, D,
        out, nullptr, D);
}

// Round 16
// 490.876 us; speedup vs baseline: 1.1227x; 1.1227x over previous
//
#include <hip/hip_runtime.h>
#include <hip/hip_bf16.h>
#include <stdint.h>

// ---------------------------------------------------------------------------
// Types
// ---------------------------------------------------------------------------
typedef __bf16 bf16x8 __attribute__((ext_vector_type(8)));
typedef float  f32x4  __attribute__((ext_vector_type(4)));

typedef __attribute__((address_space(1))) void gvoid;
typedef __attribute__((address_space(3))) void lvoid;

__device__ __forceinline__ void async16(void* lds, const void* g) {
    __builtin_amdgcn_global_load_lds((gvoid*)g, (lvoid*)lds, 16, 0, 0);
}

__device__ __forceinline__ float fexp2(float x) {
    return __builtin_amdgcn_exp2f(x);  // v_exp_f32
}

// ---------------------------------------------------------------------------
// Prep: X f32->bf16 (blocks >= 12288) + all weight transposes (blocks < 12288)
// ---------------------------------------------------------------------------
__global__ void prep_all(const float* __restrict__ X, __hip_bfloat16* __restrict__ Xb,
                         const float* __restrict__ wq, const float* __restrict__ wk,
                         const float* __restrict__ wv, const float* __restrict__ wo,
                         const float* __restrict__ w1, const float* __restrict__ w2,
                         __hip_bfloat16* __restrict__ Wcat,
                         __hip_bfloat16* __restrict__ Wot,
                         __hip_bfloat16* __restrict__ W1t,
                         __hip_bfloat16* __restrict__ W2t) {
    const int tix = blockIdx.x;
    if (tix >= 12288) {  // ---- cvt X ----
        const int bi = tix - 12288;
        const int tid = threadIdx.y * 32 + threadIdx.x;
        const long i = ((long)bi * 256 + tid) * 4;
        float4 v = *(const float4*)(X + i);
        __hip_bfloat162* d = (__hip_bfloat162*)(Xb + i);
        d[0] = __float22bfloat162_rn(make_float2(v.x, v.y));
        d[1] = __float22bfloat162_rn(make_float2(v.z, v.w));
        return;
    }
    // ---- weight transpose f32 [R][C] -> bf16 [C][R] ----
    __shared__ float t[32][33];
    const float* in;
    __hip_bfloat16* out;
    int R, C, cx, cy;
    if (tix < 4096) {
        int wid = tix >> 10, tile = tix & 1023;
        const float* srcs[4] = {wq, wk, wv, wo};
        __hip_bfloat16* dsts[4] = {Wcat, Wcat + 1024 * 1024, Wcat + 2 * 1024 * 1024, Wot};
        in = srcs[wid]; out = dsts[wid];
        R = 1024; C = 1024; cx = tile & 31; cy = tile >> 5;
    } else if (tix < 8192) {
        int tile = tix - 4096;
        in = w1; out = W1t; R = 1024; C = 4096;
        cx = tile & 127; cy = tile >> 7;
    } else {
        int tile = tix - 8192;
        in = w2; out = W2t; R = 4096; C = 1024;
        cx = tile & 31; cy = tile >> 5;
    }
    const int c0 = cx * 32, r0 = cy * 32;
    const int tx = threadIdx.x, ty = threadIdx.y;
#pragma unroll
    for (int i = 0; i < 4; ++i) {
        int r = r0 + ty + i * 8;
        t[ty + i * 8][tx] = in[(long)r * C + c0 + tx];
    }
    __syncthreads();
#pragma unroll
    for (int i = 0; i < 4; ++i) {
        int c = c0 + ty + i * 8;
        out[(long)c * R + r0 + tx] = __float2bfloat16(t[tx][ty + i * 8]);
    }
}

// ---------------------------------------------------------------------------
// Fused attention (R13-proven), 2-pass, max-free softmax (exp2).
// Phase 2: sV double-buffered; sP halved [128][64]; scalar nt stores in the
// exp loop (overlap PV); counted vmcnt(63) drain at iter end.
// ---------------------------------------------------------------------------
#define RBAR asm volatile("s_barrier" ::: "memory")

__global__ void __launch_bounds__(256, 2)
attn_fused(const __hip_bfloat16* __restrict__ QKb,
           const __hip_bfloat16* __restrict__ Vt,
           const int* __restrict__ mask,
           float* __restrict__ attn,
           __hip_bfloat16* __restrict__ Ctx) {
    __shared__ __align__(16) __hip_bfloat16 sK[128 * 64];      // 16 KB
    __shared__ __align__(16) __hip_bfloat16 sV[2][64 * 128];   // 2 x 16 KB
    __shared__ __align__(16) __hip_bfloat16 sP[128 * 64];      // 16 KB
    __shared__ float smadd[1024];

    const int tid = threadIdx.x, lane = tid & 63, wave = tid >> 6;
    const int r16 = lane & 15, kg = lane >> 4;
    const float SC2 = 0.125f * 1.44269504f;

    const int dd = blockIdx.x;
    const int wgt = (dd & 7) * 128 + (dd >> 3);
    const int xblk = wgt & 7, z = wgt >> 3;
    const int b = z >> 4, h = z & 15;
    const int row0 = xblk * 128;
    const int wrow = wave * 32;

    const __hip_bfloat16* Qz = QKb + ((long)b * 1024 + row0) * 2048 + h * 64;
    const __hip_bfloat16* Kz = QKb + (long)b * 1024 * 2048 + 1024 + h * 64;
    const __hip_bfloat16* Vz = Vt + (long)z * 64 * 1024;
    float* attnZ = attn + (long)z * 1024 * 1024 + (long)row0 * 1024;

    for (int i = tid; i < 1024; i += 256)
        smadd[i] = mask[b * 1024 + i] ? 0.f : -1.5e9f;

    bf16x8 qa[2][2];
#pragma unroll
    for (int m = 0; m < 2; ++m)
#pragma unroll
        for (int kf = 0; kf < 2; ++kf)
            qa[m][kf] = *(const bf16x8*)(Qz + (long)(wrow + m * 16 + r16) * 2048 + kf * 32 + kg * 8);

    float lrow[2][4];
#pragma unroll
    for (int m = 0; m < 2; ++m)
#pragma unroll
        for (int i = 0; i < 4; ++i) lrow[m][i] = 0.f;

    const int ssw = (r16 & 7) << 4;

    auto stageK = [&](char* dst, int ct) {
#pragma unroll
        for (int j = 0; j < 4; ++j) {
            int c = wave * 4 + j;
            int s = c * 8 + (lane >> 3);
            int cb = (lane & 7) * 16;
            async16(dst + c * 1024,
                    (const char*)(Kz + (long)(ct * 128 + s) * 2048) + (cb ^ ((s & 7) << 4)));
        }
    };
    auto stageV = [&](int ct, int buf) {
#pragma unroll
        for (int j = 0; j < 4; ++j) {
            int c = wave * 4 + j;
            int dv = c * 4 + (lane >> 4);
            int cb = (lane & 15) * 16;
            async16((char*)sV[buf] + c * 1024,
                    (const char*)(Vz + (long)dv * 1024 + ct * 128) + (cb ^ ((dv & 7) << 4)));
        }
    };

    // ---------------- phase 1: row sums (ping-pong K: sK / sV[0]) ----------------
    char* kbuf0 = (char*)sK;
    char* kbuf1 = (char*)sV[0];
    stageK(kbuf0, 0);

    for (int ct = 0; ct < 8; ++ct) {
        asm volatile("s_waitcnt vmcnt(0)" ::: "memory");
        __syncthreads();
        if (ct < 7) stageK((ct & 1) ? kbuf0 : kbuf1, ct + 1);
        const char* base = (ct & 1) ? kbuf1 : kbuf0;

        f32x4 sacc[2][8];
#pragma unroll
        for (int m = 0; m < 2; ++m)
#pragma unroll
            for (int nf = 0; nf < 8; ++nf) sacc[m][nf] = f32x4{0.f, 0.f, 0.f, 0.f};

        __builtin_amdgcn_s_setprio(1);
#pragma unroll
        for (int nf = 0; nf < 8; ++nf) {
            const char* kr = base + (nf * 16 + r16) * 128;
            bf16x8 bv0 = *(const bf16x8*)(kr + ((kg * 16) ^ ssw));
            bf16x8 bv1 = *(const bf16x8*)(kr + ((64 + kg * 16) ^ ssw));
#pragma unroll
            for (int m = 0; m < 2; ++m) {
                sacc[m][nf] = __builtin_amdgcn_mfma_f32_16x16x32_bf16(qa[m][0], bv0, sacc[m][nf], 0, 0, 0);
                sacc[m][nf] = __builtin_amdgcn_mfma_f32_16x16x32_bf16(qa[m][1], bv1, sacc[m][nf], 0, 0, 0);
            }
        }
        __builtin_amdgcn_s_setprio(0);

        float madd[8];
#pragma unroll
        for (int nf = 0; nf < 8; ++nf) madd[nf] = smadd[ct * 128 + nf * 16 + r16];

#pragma unroll
        for (int m = 0; m < 2; ++m)
#pragma unroll
            for (int i = 0; i < 4; ++i) {
                float ts = 0.f;
#pragma unroll
                for (int nf = 0; nf < 8; ++nf)
                    ts += fexp2(sacc[m][nf][i] * SC2 + madd[nf]);
#pragma unroll
                for (int o = 1; o < 16; o <<= 1) ts += __shfl_xor(ts, o);
                lrow[m][i] += ts;
            }
    }

    float rinv[2][4];
#pragma unroll
    for (int m = 0; m < 2; ++m)
#pragma unroll
        for (int i = 0; i < 4; ++i) rinv[m][i] = 1.0f / lrow[m][i];

    f32x4 oacc[2][4];
#pragma unroll
    for (int m = 0; m < 2; ++m)
#pragma unroll
        for (int nf = 0; nf < 4; ++nf) oacc[m][nf] = f32x4{0.f, 0.f, 0.f, 0.f};

    // ---------------- phase 2: P write + PV ----------------
    __syncthreads();
    stageK((char*)sK, 0);
    stageV(0, 0);
    asm volatile("s_waitcnt vmcnt(0)" ::: "memory");
    __syncthreads();

    for (int ct = 0; ct < 8; ++ct) {
        f32x4 sacc[2][8];
#pragma unroll
        for (int m = 0; m < 2; ++m)
#pragma unroll
            for (int nf = 0; nf < 8; ++nf) sacc[m][nf] = f32x4{0.f, 0.f, 0.f, 0.f};

        __builtin_amdgcn_s_setprio(1);
#pragma unroll
        for (int nf = 0; nf < 8; ++nf) {
            const char* kr = (const char*)sK + (nf * 16 + r16) * 128;
            bf16x8 bv0 = *(const bf16x8*)(kr + ((kg * 16) ^ ssw));
            bf16x8 bv1 = *(const bf16x8*)(kr + ((64 + kg * 16) ^ ssw));
#pragma unroll
            for (int m = 0; m < 2; ++m) {
                sacc[m][nf] = __builtin_amdgcn_mfma_f32_16x16x32_bf16(qa[m][0], bv0, sacc[m][nf], 0, 0, 0);
                sacc[m][nf] = __builtin_amdgcn_mfma_f32_16x16x32_bf16(qa[m][1], bv1, sacc[m][nf], 0, 0, 0);
            }
        }
        __builtin_amdgcn_s_setprio(0);

        RBAR;
        if (ct < 7) {
            stageK((char*)sK, ct + 1);
            stageV(ct + 1, (ct + 1) & 1);
        }
        asm volatile("" ::: "memory");  // pin: DMA issue BEFORE the stores

        float madd[8];
#pragma unroll
        for (int nf = 0; nf < 8; ++nf) madd[nf] = smadd[ct * 128 + nf * 16 + r16];

        const char* sVb = (const char*)sV[ct & 1];

#pragma unroll
        for (int half = 0; half < 2; ++half) {
            // ---- P write for this 64-col half (attn f32 nt + sP bf16) ----
#pragma unroll
            for (int m = 0; m < 2; ++m)
#pragma unroll
                for (int nf = 0; nf < 4; ++nf) {
                    const int nfg = half * 4 + nf;
                    const int scol = nfg * 16 + r16;   // within 128
                    const int scl = nf * 16 + r16;     // within half
#pragma unroll
                    for (int i = 0; i < 4; ++i) {
                        int q = wrow + m * 16 + kg * 4 + i;
                        float p = fexp2(sacc[m][nfg][i] * SC2 + madd[nfg]) * rinv[m][i];
                        __builtin_nontemporal_store(p, attnZ + (long)q * 1024 + ct * 128 + scol);
                        *(__hip_bfloat16*)((char*)sP + q * 128 + ((scl * 2) ^ ((q & 7) << 4))) =
                            __float2bfloat16(p);
                    }
                }

            // ---- PV for this half (own-wave sP rows; DS in-order per wave) ----
            __builtin_amdgcn_s_setprio(1);
#pragma unroll
            for (int ks = 0; ks < 2; ++ks) {
                const int ksg = half * 2 + ks;
                bf16x8 pa[2], vv[4];
#pragma unroll
                for (int m = 0; m < 2; ++m)
                    pa[m] = *(const bf16x8*)((const char*)sP + (wrow + m * 16 + r16) * 128 +
                                             ((ks * 64 + kg * 16) ^ ssw));
#pragma unroll
                for (int nf = 0; nf < 4; ++nf)
                    vv[nf] = *(const bf16x8*)(sVb + (nf * 16 + r16) * 256 +
                                              ((ksg * 64 + kg * 16) ^ ssw));
#pragma unroll
                for (int m = 0; m < 2; ++m)
#pragma unroll
                    for (int nf = 0; nf < 4; ++nf)
                        oacc[m][nf] = __builtin_amdgcn_mfma_f32_16x16x32_bf16(pa[m], vv[nf], oacc[m][nf], 0, 0, 0);
            }
            __builtin_amdgcn_s_setprio(0);
        }

        if (ct < 7) {
            // 8 K/V DMAs are OLDER than the 64 stores above: waiting to <=63
            // outstanding retires the DMAs while stores keep draining.
            asm volatile("s_waitcnt vmcnt(63)" ::: "memory");
            RBAR;
        }
    }

#pragma unroll
    for (int m = 0; m < 2; ++m)
#pragma unroll
        for (int nf = 0; nf < 4; ++nf)
#pragma unroll
            for (int i = 0; i < 4; ++i) {
                int q = wrow + m * 16 + kg * 4 + i;
                Ctx[((long)b * 1024 + row0 + q) * 1024 + h * 64 + nf * 16 + r16] =
                    __float2bfloat16(oacc[m][nf][i]);
            }
}

// ---------------------------------------------------------------------------
// Shared GEMM macros
// ---------------------------------------------------------------------------
#define RDA(BUF, PM, ML, KS) \
    (*(const bf16x8*)(aRd + (BUF)*32768 + (PM)*16384 + (ML)*2048 + ((((KS)*64) + kg*16) ^ sw)))
#define RDB(BUF, PN, NL, KS) \
    (*(const bf16x8*)(bRd + (BUF)*32768 + (PN)*16384 + (NL)*2048 + ((((KS)*64) + kg*16) ^ sw)))
#define LOAD_A(BUF, PM)                          \
    _Pragma("unroll") for (int ml = 0; ml < 4; ++ml) \
    _Pragma("unroll") for (int ks = 0; ks < 2; ++ks) \
        a[ml][ks] = RDA(BUF, PM, ml, ks)
#define LOAD_B(DST, BUF, PN)                     \
    _Pragma("unroll") for (int nl = 0; nl < 2; ++nl) \
    _Pragma("unroll") for (int ks = 0; ks < 2; ++ks) \
        DST[nl][ks] = RDB(BUF, PN, nl, ks)
#define MFMA16(PM, PN, BB)                                                   \
    __builtin_amdgcn_s_setprio(1);                                           \
    _Pragma("unroll") for (int ks = 0; ks < 2; ++ks)                         \
    _Pragma("unroll") for (int ml = 0; ml < 4; ++ml)                         \
    _Pragma("unroll") for (int nl = 0; nl < 2; ++nl)                         \
        acc[(PM)*4 + ml][(PN)*2 + nl] = __builtin_amdgcn_mfma_f32_16x16x32_bf16( \
            a[ml][ks], BB[nl][ks], acc[(PM)*4 + ml][(PN)*2 + nl], 0, 0, 0);  \
    __builtin_amdgcn_s_setprio(0)
#define BAR asm volatile("s_barrier" ::: "memory")
#define RDB128(BUF, NL, KS) \
    (*(const bf16x8*)(bRd + (BUF)*16384 + (NL)*2048 + ((((KS)*64) + kg*16) ^ sw)))
#define LOAD_B128(DST, BUF)                      \
    _Pragma("unroll") for (int nl = 0; nl < 2; ++nl) \
    _Pragma("unroll") for (int ks = 0; ks < 2; ++ks) \
        DST[nl][ks] = RDB128(BUF, nl, ks)
#define MFMA16N(PM, BB)                                                      \
    __builtin_amdgcn_s_setprio(1);                                           \
    _Pragma("unroll") for (int ks = 0; ks < 2; ++ks)                         \
    _Pragma("unroll") for (int ml = 0; ml < 4; ++ml)                         \
    _Pragma("unroll") for (int nl = 0; nl < 2; ++nl)                         \
        acc[(PM)*4 + ml][nl] = __builtin_amdgcn_mfma_f32_16x16x32_bf16(      \
            a[ml][ks], BB[nl][ks], acc[(PM)*4 + ml][nl], 0, 0, 0);           \
    __builtin_amdgcn_s_setprio(0)

// ---------------------------------------------------------------------------
// 256x256 8-phase GEMM — FFN1 (N=4096).
// ---------------------------------------------------------------------------
__global__ void __launch_bounds__(512, 2)
gemm256(const __hip_bfloat16* __restrict__ A, int lda,
        const __hip_bfloat16* __restrict__ Bt, int ldb,
        int K, int Mtiles,
        const float* __restrict__ bias, int relu,
        __hip_bfloat16* __restrict__ C, int ldc) {
    __shared__ __align__(16) char lds[131072];
    const int NT = K >> 6;
    const int tid = threadIdx.x, lane = tid & 63, wave = tid >> 6;
    const int r16 = lane & 15, kg = lane >> 4;
    const int wr = wave >> 2, wc = wave & 3;
    const int sw = (r16 & 7) << 4;

    const int nwg = gridDim.x;
    const int q8 = nwg >> 3, r8 = nwg & 7;
    const int xcd = blockIdx.x & 7, rest = blockIdx.x >> 3;
    const int wg = (xcd < r8 ? xcd * (q8 + 1) : r8 * (q8 + 1) + (xcd - r8) * q8) + rest;
    const int tm = wg % Mtiles, tn = wg / Mtiles;
    const long row0 = (long)tm * 256, col0 = (long)tn * 256;

    const int idx = tid >> 3;
    const int slotp = ((tid & 7) ^ (idx & 7)) * 8;
    const __hip_bfloat16* aSrc[4];
    const __hip_bfloat16* bSrc[4];
#pragma unroll
    for (int j = 0; j < 4; ++j) {
        long ar = row0 + (j & 1) * 128 + (j >> 1) * 64 + idx;
        aSrc[j] = A + ar * lda + slotp;
        long br = col0 + ((j & 1) * 2 + (tid >> 8)) * 64 + (j >> 1) * 32 + (idx & 31);
        bSrc[j] = Bt + br * ldb + slotp;
    }

    char* ldsA = lds;
    char* ldsB = lds + 65536;
    const int stDst = wave * 1024;
    auto stA = [&](int v, int j) {
        async16(ldsA + ((v & 1) << 15) + (j << 13) + stDst, aSrc[j] + (v << 6));
    };
    auto stB = [&](int v, int j) {
        async16(ldsB + ((v & 1) << 15) + (j << 13) + stDst, bSrc[j] + (v << 6));
    };

    stA(0, 0); stA(0, 1); stB(0, 0); stB(0, 1);
    stA(0, 2); stA(0, 3); stB(0, 2); stB(0, 3);
    stA(1, 0); stA(1, 1); stB(1, 0); stB(1, 1);
    asm volatile("s_waitcnt vmcnt(4)" ::: "memory");
    BAR;

    f32x4 acc[8][4] = {};
    const char* aRd = ldsA + wr * 8192 + r16 * 128;
    const char* bRd = ldsB + wc * 4096 + r16 * 128;

    for (int u = 0; u < NT; u += 2) {
        const bool more = (u + 2) < NT;
        bf16x8 a[4][2], b0[2][2], b1[2][2];

        LOAD_A(0, 0);
        LOAD_B(b0, 0, 0);
        stA(u + 1, 2); stA(u + 1, 3);
        MFMA16(0, 0, b0);
        BAR;

        LOAD_B(b1, 0, 1);
        stB(u + 1, 2); stB(u + 1, 3);
        MFMA16(0, 1, b1);
        BAR;

        LOAD_A(0, 1);
        if (more) { stA(u + 2, 0); stA(u + 2, 1); }
        MFMA16(1, 0, b0);
        BAR;

        if (more) {
            stB(u + 2, 0); stB(u + 2, 1);
            asm volatile("s_waitcnt vmcnt(4)" ::: "memory");
        } else {
            asm volatile("s_waitcnt vmcnt(0)" ::: "memory");
        }
        MFMA16(1, 1, b1);
        BAR;

        LOAD_A(1, 0);
        LOAD_B(b0, 1, 0);
        if (more) { stA(u + 2, 2); stA(u + 2, 3); }
        MFMA16(0, 0, b0);
        BAR;

        LOAD_B(b1, 1, 1);
        if (more) { stB(u + 2, 2); stB(u + 2, 3); }
        MFMA16(0, 1, b1);
        BAR;

        LOAD_A(1, 1);
        if (more) { stA(u + 3, 0); stA(u + 3, 1); }
        MFMA16(1, 0, b0);
        BAR;

        if (more) {
            stB(u + 3, 0); stB(u + 3, 1);
            asm volatile("s_waitcnt vmcnt(4)" ::: "memory");
        }
        MFMA16(1, 1, b1);
        BAR;
    }

    const long crow = row0 + wr * 128, ccol = col0 + wc * 64;
#pragma unroll
    for (int mf = 0; mf < 8; ++mf)
#pragma unroll
        for (int nf = 0; nf < 4; ++nf) {
            const long col = ccol + nf * 16 + r16;
            const float bs = bias ? bias[col] : 0.f;
#pragma unroll
            for (int i = 0; i < 4; ++i) {
                const long row = crow + mf * 16 + kg * 4 + i;
                float v = acc[mf][nf][i] + bs;
                if (relu) v = fmaxf(v, 0.f);
                C[row * (long)ldc + col] = __float2bfloat16(v);
            }
        }
}

// ---------------------------------------------------------------------------
// Merged QK + V dispatcher (R13-proven).
// ---------------------------------------------------------------------------
__global__ void __launch_bounds__(512, 2)
gemm_qkv(const __hip_bfloat16* __restrict__ A,
         const __hip_bfloat16* __restrict__ Wcat,
         __hip_bfloat16* __restrict__ QKb,
         __hip_bfloat16* __restrict__ Vt) {
    __shared__ __align__(16) char lds[131072];
    const int tid = threadIdx.x, lane = tid & 63, wave = tid >> 6;
    const int r16 = lane & 15, kg = lane >> 4;
    const int wr = wave >> 2, wc = wave & 3;
    const int sw = (r16 & 7) << 4;
    const int idx = tid >> 3;
    const int slotp = ((tid & 7) ^ (idx & 7)) * 8;
    const int stDst = wave * 1024;
    constexpr int NT = 16;  // K=1024

    if (blockIdx.x < 256) {
        const int id = blockIdx.x;
        const int xcd = id & 7, rest = id >> 3;
        const int wg = xcd * 32 + rest;
        const int tm = wg & 31, tn = wg >> 5;
        const long row0 = (long)tm * 256, col0 = (long)tn * 256;

        const __hip_bfloat16* aSrc[4];
        const __hip_bfloat16* bSrc[4];
#pragma unroll
        for (int j = 0; j < 4; ++j) {
            long ar = row0 + (j & 1) * 128 + (j >> 1) * 64 + idx;
            aSrc[j] = A + ar * 1024 + slotp;
            long br = col0 + ((j & 1) * 2 + (tid >> 8)) * 64 + (j >> 1) * 32 + (idx & 31);
            bSrc[j] = Wcat + br * 1024 + slotp;
        }

        char* ldsA = lds;
        char* ldsB = lds + 65536;
        auto stA = [&](int v, int j) {
            async16(ldsA + ((v & 1) << 15) + (j << 13) + stDst, aSrc[j] + (v << 6));
        };
        auto stB = [&](int v, int j) {
            async16(ldsB + ((v & 1) << 15) + (j << 13) + stDst, bSrc[j] + (v << 6));
        };

        stA(0, 0); stA(0, 1); stB(0, 0); stB(0, 1);
        stA(0, 2); stA(0, 3); stB(0, 2); stB(0, 3);
        stA(1, 0); stA(1, 1); stB(1, 0); stB(1, 1);
        asm volatile("s_waitcnt vmcnt(4)" ::: "memory");
        BAR;

        f32x4 acc[8][4] = {};
        const char* aRd = ldsA + wr * 8192 + r16 * 128;
        const char* bRd = ldsB + wc * 4096 + r16 * 128;

        for (int u = 0; u < NT; u += 2) {
            const bool more = (u + 2) < NT;
            bf16x8 a[4][2], b0[2][2], b1[2][2];

            LOAD_A(0, 0);
            LOAD_B(b0, 0, 0);
            stA(u + 1, 2); stA(u + 1, 3);
            MFMA16(0, 0, b0);
            BAR;

            LOAD_B(b1, 0, 1);
            stB(u + 1, 2); stB(u + 1, 3);
            MFMA16(0, 1, b1);
            BAR;

            LOAD_A(0, 1);
            if (more) { stA(u + 2, 0); stA(u + 2, 1); }
            MFMA16(1, 0, b0);
            BAR;

            if (more) {
                stB(u + 2, 0); stB(u + 2, 1);
                asm volatile("s_waitcnt vmcnt(4)" ::: "memory");
            } else {
                asm volatile("s_waitcnt vmcnt(0)" ::: "memory");
            }
            MFMA16(1, 1, b1);
            BAR;

            LOAD_A(1, 0);
            LOAD_B(b0, 1, 0);
            if (more) { stA(u + 2, 2); stA(u + 2, 3); }
            MFMA16(0, 0, b0);
            BAR;

            LOAD_B(b1, 1, 1);
            if (more) { stB(u + 2, 2); stB(u + 2, 3); }
            MFMA16(0, 1, b1);
            BAR;

            LOAD_A(1, 1);
            if (more) { stA(u + 3, 0); stA(u + 3, 1); }
            MFMA16(1, 0, b0);
            BAR;

            if (more) {
                stB(u + 3, 0); stB(u + 3, 1);
                asm volatile("s_waitcnt vmcnt(4)" ::: "memory");
            }
            MFMA16(1, 1, b1);
            BAR;
        }

        const long crow = row0 + wr * 128, ccol = col0 + wc * 64;
#pragma unroll
        for (int mf = 0; mf < 8; ++mf)
#pragma unroll
            for (int nf = 0; nf < 4; ++nf) {
                const long col = ccol + nf * 16 + r16;
#pragma unroll
                for (int i = 0; i < 4; ++i) {
                    const long row = crow + mf * 16 + kg * 4 + i;
                    QKb[row * 2048 + col] = __float2bfloat16(acc[mf][nf][i]);
                }
            }
    } else {
        const int id = blockIdx.x - 256;
        const int xcd = id & 7, rest = id >> 3;
        const int wg = xcd * 32 + rest;
        const int tm = wg & 31, tn = wg >> 5;
        const long row0 = (long)tm * 256, col0 = (long)tn * 128;
        const __hip_bfloat16* Bt = Wcat + (long)2048 * 1024;

        const __hip_bfloat16* aSrc[4];
        const __hip_bfloat16* bSrc[2];
#pragma unroll
        for (int j = 0; j < 4; ++j) {
            long ar = row0 + (j & 1) * 128 + (j >> 1) * 64 + idx;
            aSrc[j] = A + ar * 1024 + slotp;
        }
#pragma unroll
        for (int j = 0; j < 2; ++j) {
            long br = col0 + j * 64 + idx;
            bSrc[j] = Bt + br * 1024 + slotp;
        }

        char* ldsA = lds;
        char* ldsB = lds + 65536;
        auto stA = [&](int v, int j) {
            async16(ldsA + ((v & 1) << 15) + (j << 13) + stDst, aSrc[j] + (v << 6));
        };
        auto stB = [&](int v, int j) {
            async16(ldsB + ((v & 1) << 14) + (j << 13) + stDst, bSrc[j] + (v << 6));
        };

        stA(0, 0); stA(0, 1); stA(0, 2); stA(0, 3);
        stB(0, 0); stB(0, 1);
        stA(1, 0); stA(1, 1);
        stB(1, 0); stB(1, 1);
        asm volatile("s_waitcnt vmcnt(4)" ::: "memory");
        BAR;

        f32x4 acc[8][2] = {};
        const char* aRd = ldsA + wr * 8192 + r16 * 128;
        const char* bRd = ldsB + wc * 4096 + r16 * 128;

        for (int u = 0; u < NT; u += 2) {
            const bool more = (u + 2) < NT;
            bf16x8 a[4][2], b0[2][2], b1[2][2];

            LOAD_A(0, 0);
            LOAD_B128(b0, 0);
            stA(u + 1, 2); stA(u + 1, 3);
            MFMA16N(0, b0);
            BAR;

            LOAD_A(0, 1);
            if (more) {
                stA(u + 2, 0); stA(u + 2, 1);
                stB(u + 2, 0); stB(u + 2, 1);
                asm volatile("s_waitcnt vmcnt(4)" ::: "memory");
            } else {
                asm volatile("s_waitcnt vmcnt(0)" ::: "memory");
            }
            MFMA16N(1, b0);
            BAR;

            LOAD_A(1, 0);
            LOAD_B128(b1, 1);
            if (more) { stA(u + 2, 2); stA(u + 2, 3); }
            MFMA16N(0, b1);
            BAR;

            LOAD_A(1, 1);
            if (more) {
                stA(u + 3, 0); stA(u + 3, 1);
                stB(u + 3, 0); stB(u + 3, 1);
                asm volatile("s_waitcnt vmcnt(4)" ::: "memory");
            }
            MFMA16N(1, b1);
            BAR;
        }

        __hip_bfloat16* sT = (__hip_bfloat16*)lds;
        {
            const int cls = wc * 32;
            const int rls = wr * 128 + kg * 4;
#pragma unroll
            for (int mf = 0; mf < 8; ++mf)
#pragma unroll
                for (int nf = 0; nf < 2; ++nf) {
                    int cl = cls + nf * 16 + r16;
                    int rl = rls + mf * 16;
                    __hip_bfloat162 lo = __float22bfloat162_rn(make_float2(acc[mf][nf][0], acc[mf][nf][1]));
                    __hip_bfloat162 hi = __float22bfloat162_rn(make_float2(acc[mf][nf][2], acc[mf][nf][3]));
                    *(__hip_bfloat162*)(&sT[cl * 264 + rl]) = lo;
                    *(__hip_bfloat162*)(&sT[cl * 264 + rl + 2]) = hi;
                }
        }
        __syncthreads();
        {
            const int b = (int)(row0 >> 10);
            const int s_base = (int)(row0 & 1023);
#pragma unroll
            for (int j = 0; j < 8; ++j) {
                int dl = wave * 16 + j * 2 + (lane >> 5);
                int sc = (lane & 31) * 8;
                bf16x8 v = *(const bf16x8*)(&sT[dl * 264 + sc]);
                int dg = (int)col0 + dl;
                int z = b * 16 + (dg >> 6);
                int d = dg & 63;
                *(bf16x8*)(Vt + ((long)z * 64 + d) * 1024 + s_base + sc) = v;
            }
        }
    }
}

// ---------------------------------------------------------------------------
// 256x128-tile 4-phase GEMM — N=1024 shapes (Wo, FFN2): 256 blocks.
// ---------------------------------------------------------------------------
__global__ void __launch_bounds__(512, 2)
gemm256n128(const __hip_bfloat16* __restrict__ A, int lda,
            const __hip_bfloat16* __restrict__ Bt, int ldb,
            int K, int Mtiles,
            const float* __restrict__ bias, int relu,
            const float* __restrict__ resf,
            const __hip_bfloat16* __restrict__ resb, int ldres,
            float* __restrict__ Cf, __hip_bfloat16* __restrict__ Cb, int ldc) {
    __shared__ __align__(16) char lds[98304];  // A 2x32KB + B 2x16KB
    const int NT = K >> 6;
    const int tid = threadIdx.x, lane = tid & 63, wave = tid >> 6;
    const int r16 = lane & 15, kg = lane >> 4;
    const int wr = wave >> 2, wc = wave & 3;
    const int sw = (r16 & 7) << 4;

    const int nwg = gridDim.x;
    const int q8 = nwg >> 3, r8 = nwg & 7;
    const int xcd = blockIdx.x & 7, rest = blockIdx.x >> 3;
    const int wg = (xcd < r8 ? xcd * (q8 + 1) : r8 * (q8 + 1) + (xcd - r8) * q8) + rest;
    const int tm = wg % Mtiles, tn = wg / Mtiles;
    const long row0 = (long)tm * 256, col0 = (long)tn * 128;

    const int idx = tid >> 3;
    const int slotp = ((tid & 7) ^ (idx & 7)) * 8;
    const __hip_bfloat16* aSrc[4];
    const __hip_bfloat16* bSrc[2];
#pragma unroll
    for (int j = 0; j < 4; ++j) {
        long ar = row0 + (j & 1) * 128 + (j >> 1) * 64 + idx;
        aSrc[j] = A + ar * lda + slotp;
    }
#pragma unroll
    for (int j = 0; j < 2; ++j) {
        long br = col0 + j * 64 + idx;
        bSrc[j] = Bt + br * ldb + slotp;
    }

    char* ldsA = lds;
    char* ldsB = lds + 65536;
    const int stDst = wave * 1024;
    auto stA = [&](int v, int j) {
        async16(ldsA + ((v & 1) << 15) + (j << 13) + stDst, aSrc[j] + (v << 6));
    };
    auto stB = [&](int v, int j) {
        async16(ldsB + ((v & 1) << 14) + (j << 13) + stDst, bSrc[j] + (v << 6));
    };

    stA(0, 0); stA(0, 1); stA(0, 2); stA(0, 3);
    stB(0, 0); stB(0, 1);
    stA(1, 0); stA(1, 1);
    stB(1, 0); stB(1, 1);
    asm volatile("s_waitcnt vmcnt(4)" ::: "memory");
    BAR;

    f32x4 acc[8][2] = {};
    const char* aRd = ldsA + wr * 8192 + r16 * 128;
    const char* bRd = ldsB + wc * 4096 + r16 * 128;

    for (int u = 0; u < NT; u += 2) {
        const bool more = (u + 2) < NT;
        bf16x8 a[4][2], b0[2][2], b1[2][2];

        LOAD_A(0, 0);
        LOAD_B128(b0, 0);
        stA(u + 1, 2); stA(u + 1, 3);
        MFMA16N(0, b0);
        BAR;

        LOAD_A(0, 1);
        if (more) {
            stA(u + 2, 0); stA(u + 2, 1);
            stB(u + 2, 0); stB(u + 2, 1);
            asm volatile("s_waitcnt vmcnt(4)" ::: "memory");
        } else {
            asm volatile("s_waitcnt vmcnt(0)" ::: "memory");
        }
        MFMA16N(1, b0);
        BAR;

        LOAD_A(1, 0);
        LOAD_B128(b1, 1);
        if (more) { stA(u + 2, 2); stA(u + 2, 3); }
        MFMA16N(0, b1);
        BAR;

        LOAD_A(1, 1);
        if (more) {
            stA(u + 3, 0); stA(u + 3, 1);
            stB(u + 3, 0); stB(u + 3, 1);
            asm volatile("s_waitcnt vmcnt(4)" ::: "memory");
        }
        MFMA16N(1, b1);
        BAR;
    }

    const long crow = row0 + wr * 128, ccol = col0 + wc * 32;
#pragma unroll
    for (int mf = 0; mf < 8; ++mf)
#pragma unroll
        for (int nf = 0; nf < 2; ++nf) {
            const long col = ccol + nf * 16 + r16;
            const float bs = bias ? bias[col] : 0.f;
#pragma unroll
            for (int i = 0; i < 4; ++i) {
                const long row = crow + mf * 16 + kg * 4 + i;
                float v = acc[mf][nf][i] + bs;
                if (relu) v = fmaxf(v, 0.f);
                if (resf) v += resf[row * (long)ldres + col];
                if (resb) v += __bfloat162float(resb[row * (long)ldres + col]);
                const long off = row * (long)ldc + col;
                if (Cf) __builtin_nontemporal_store(v, Cf + off);
                if (Cb) Cb[off] = __float2bfloat16(v);
            }
        }
}

// ---------------------------------------------------------------------------
// Launch
// ---------------------------------------------------------------------------
extern "C" void kernel_launch(void* const* d_in, const int* in_sizes, int n_in,
                              void* d_out, int out_size, void* d_ws, size_t ws_size,
                              hipStream_t stream) {
    const int B = 8, S = 1024, D = 1024, DFF = 4096;
    const long SD = (long)B * S * D;  // 8M

    const float* X  = (const float*)d_in[0];
    const int*  msk = (const int*)d_in[1];
    const float* wq = (const float*)d_in[3];
    const float* wk = (const float*)d_in[4];
    const float* wv = (const float*)d_in[5];
    const float* wo = (const float*)d_in[6];
    const float* w1 = (const float*)d_in[7];
    const float* b1 = (const float*)d_in[8];
    const float* w2 = (const float*)d_in[9];
    const float* b2 = (const float*)d_in[10];

    float* out  = (float*)d_out;
    float* attn = out + SD;

    char* ws = (char*)d_ws;
    auto alloc = [&](size_t bytes) {
        char* p = ws;
        ws += (bytes + 255) & ~(size_t)255;
        return p;
    };
    __hip_bfloat16* Xb   = (__hip_bfloat16*)alloc(SD * 2);
    __hip_bfloat16* QKb  = (__hip_bfloat16*)alloc(SD * 4);   // [8192][2048]
    __hip_bfloat16* Vt   = (__hip_bfloat16*)alloc(SD * 2);   // [128][64][1024]
    __hip_bfloat16* Ctx  = (__hip_bfloat16*)alloc(SD * 2);
    __hip_bfloat16* EncB = (__hip_bfloat16*)alloc(SD * 2);
    __hip_bfloat16* Hb   = (__hip_bfloat16*)alloc((long)B * S * DFF * 2);
    __hip_bfloat16* Wcat = (__hip_bfloat16*)alloc((long)3 * D * D * 2);  // [3072][1024]
    __hip_bfloat16* Wot  = (__hip_bfloat16*)alloc((long)D * D * 2);
    __hip_bfloat16* W1t  = (__hip_bfloat16*)alloc((long)D * DFF * 2);
    __hip_bfloat16* W2t  = (__hip_bfloat16*)alloc((long)D * DFF * 2);
    (void)ws_size; (void)in_sizes; (void)n_in; (void)out_size;

    dim3 tb(32, 8);
    prep_all<<<dim3(12288 + 8192), tb, 0, stream>>>(X, Xb, wq, wk, wv, wo, w1, w2,
                                                    Wcat, Wot, W1t, W2t);

    // QK [8192][2048] + V->Vt in ONE dispatch (512 blocks)
    gemm_qkv<<<dim3(512), 512, 0, stream>>>(Xb, Wcat, QKb, Vt);

    // fused attention: attn f32 + ctx bf16
    attn_fused<<<dim3(1024), 256, 0, stream>>>(QKb, Vt, msk, attn, Ctx);

    // enc = ctx @ Wo + X  -> bf16   (256x128, 256 blocks)
    gemm256n128<<<dim3(32 * 8), 512, 0, stream>>>(
        Ctx, D, Wot, D, D, 32,
        nullptr, 0, X, nullptr, D,
        nullptr, EncB, D);

    // h = relu(enc @ W1 + b1)   (256^2, 512 blocks)
    gemm256<<<dim3(32 * 16), 512, 0, stream>>>(
        EncB, D, W1t, D, D, 32, b1, 1, Hb, DFF);

    // out = h @ W2 + b2 + enc (bf16 residual)   (256x128, 256 blocks)
    gemm256n128<<<dim3(32 * 8), 512, 0, stream>>>(
        Hb, DFF, W2t, DFF, DFF, 32,
        b2, 0, nullptr, EncB, D,
        out, nullptr, D);
}